// Round 2
// baseline (527.726 us; speedup 1.0000x reference)
//
#include <hip/hip_runtime.h>

// Bilinear resample with zero-padding OOB semantics (tf resampler behavior).
// imgs: (B,H,W,1) f32, dvfs: (B,H,W,2) f32 (ch0 = x offset, ch1 = y offset)
// out:  (B,H,W,1) f32.  B=32, H=W=1024.
//
// v3: LDS-staged tiled gather. Each 256-thread block computes a 64x64 output
// tile and stages the 81x81 input neighborhood (halo=8, >> max|N(0,1)| over
// 67M draws ~5.8) into LDS with coalesced loads. The 4 divergent corner
// gathers become LDS reads (~6 cyc/wave each) instead of ~110 serialized
// cache-line transactions per wave at the TCP. Staged tile holds 0.0f for
// out-of-image texels, so zero-padding semantics are free on the LDS path.
// Out-of-halo displacements (never in practice) fall back to global gathers.

#define H_DIM 1024
#define W_DIM 1024
#define HW_SHIFT 20
#define TILE 64
#define HALO 8
#define S_DIM (TILE + 2 * HALO + 1)   // 81 staged rows/cols; odd stride -> bank spread

__device__ __forceinline__ float gather_zp(const float* __restrict__ img,
                                           int yy, int xx) {
    bool valid = (xx >= 0) & (xx < W_DIM) & (yy >= 0) & (yy < H_DIM);
    int xc = min(max(xx, 0), W_DIM - 1);
    int yc = min(max(yy, 0), H_DIM - 1);
    float v = img[yc * W_DIM + xc];
    return valid ? v : 0.0f;
}

__global__ __launch_bounds__(256) void bilerp_kernel(
        const float* __restrict__ imgs,
        const float* __restrict__ dvfs,
        float* __restrict__ out) {
    __shared__ float tile[S_DIM * S_DIM];   // 81*81*4 = 25.6 KB

    const int gx0 = blockIdx.x * TILE;
    const int gy0 = blockIdx.y * TILE;
    const int b   = blockIdx.z;
    const int tid = threadIdx.x;

    const float* __restrict__ img = imgs + ((long long)b << HW_SHIFT);

    // ---- stage 81x81 neighborhood (zero for out-of-image) ----
    const int x_base = gx0 - HALO;
    const int y_base = gy0 - HALO;
    for (int idx = tid; idx < S_DIM * S_DIM; idx += 256) {
        int r = idx / S_DIM;                // const div -> magic mul
        int c = idx - r * S_DIM;
        int gy = y_base + r;
        int gx = x_base + c;
        float v = 0.0f;
        if ((unsigned)gy < (unsigned)H_DIM && (unsigned)gx < (unsigned)W_DIM)
            v = img[(gy << 10) + gx];
        tile[idx] = v;
    }
    __syncthreads();

    // ---- 64x64 outputs: thread (tx,ty) does rows ty, ty+4, ..., ty+60 ----
    const int tx = tid & 63;
    const int ty = tid >> 6;
    const float* __restrict__ dv_img =
        dvfs + (((long long)b << HW_SHIFT) << 1);
    float* __restrict__ out_img = out + ((long long)b << HW_SHIFT);

    for (int i = 0; i < 16; ++i) {
        int y = gy0 + (i << 2) + ty;
        int x = gx0 + tx;
        int pix = (y << 10) + x;

        union { double d64; float2 f2; } cvt;
        cvt.d64 = __builtin_nontemporal_load(
            reinterpret_cast<const double*>(dv_img) + pix);
        float dx = cvt.f2.x;
        float dy = cvt.f2.y;

        float fx = (float)x + dx;
        float fy = (float)y + dy;
        float x0f = floorf(fx);
        float y0f = floorf(fy);
        float wx = fx - x0f;
        float wy = fy - y0f;
        int x0 = (int)x0f;
        int y0 = (int)y0f;

        int lx = x0 - x_base;     // need lx in [0, S_DIM-2] so lx+1 valid
        int ly = y0 - y_base;

        float v00, v01, v10, v11;
        if ((unsigned)lx < (unsigned)(S_DIM - 1) &&
            (unsigned)ly < (unsigned)(S_DIM - 1)) {
            const float* p = &tile[ly * S_DIM + lx];
            v00 = p[0];
            v01 = p[1];
            v10 = p[S_DIM];
            v11 = p[S_DIM + 1];
        } else {                   // out-of-halo: ~never taken
            v00 = gather_zp(img, y0,     x0);
            v01 = gather_zp(img, y0,     x0 + 1);
            v10 = gather_zp(img, y0 + 1, x0);
            v11 = gather_zp(img, y0 + 1, x0 + 1);
        }

        float res = v00 * (1.0f - wx) * (1.0f - wy)
                  + v01 * wx          * (1.0f - wy)
                  + v10 * (1.0f - wx) * wy
                  + v11 * wx          * wy;

        __builtin_nontemporal_store(res, out_img + pix);
    }
}

extern "C" void kernel_launch(void* const* d_in, const int* in_sizes, int n_in,
                              void* d_out, int out_size, void* d_ws, size_t ws_size,
                              hipStream_t stream) {
    const float* imgs = (const float*)d_in[0];
    const float* dvfs = (const float*)d_in[1];
    float* out = (float*)d_out;

    dim3 grid(W_DIM / TILE, H_DIM / TILE, 32);   // 16 x 16 x 32 = 8192 blocks
    bilerp_kernel<<<grid, 256, 0, stream>>>(imgs, dvfs, out);
}

// Round 3
// 522.370 us; speedup vs baseline: 1.0103x; 1.0103x over previous
//
#include <hip/hip_runtime.h>

// Bilinear resample, zero-padding OOB (tf resampler semantics).
// imgs: (B,H,W,1) f32, dvfs: (B,H,W,2) f32 (ch0=x offset, ch1=y offset)
// out:  (B,H,W,1) f32.  B=32, H=W=1024.
//
// v4: LDS-staged 64x64 tile, with v3's overheads removed:
//  - staging via float4 (20 float4/row, 80 rows, ~6 iters/thread) instead of
//    26 scalar-dword iterations with div-by-81.
//  - all 16 dvf loads issued BEFORE staging; they drain under staging+barrier,
//    so the compute loop has no global-load latency on its critical path.
//  - fma-lerp combine (6 VALU) instead of expanded 4-term form.
// Halo=8 >> max|N(0,1)| over 67M draws (~5.8); out-of-halo lanes (never in
// practice) fall back to global gathers. Staged tile holds 0 for out-of-image
// texels so zero-padding is free on the LDS path. All float4 stages are fully
// in- or out-of-bounds (x_base and image edges are 4-aligned): no straddle.

#define H_DIM 1024
#define W_DIM 1024
#define HW_SHIFT 20
#define TILE 64
#define HALO 8
#define S_W 80              // staged width in floats
#define S_H 80              // staged height
#define S_W4 20             // float4 per staged row

__device__ __forceinline__ float gather_zp(const float* __restrict__ img,
                                           int yy, int xx) {
    bool valid = (xx >= 0) & (xx < W_DIM) & (yy >= 0) & (yy < H_DIM);
    int xc = min(max(xx, 0), W_DIM - 1);
    int yc = min(max(yy, 0), H_DIM - 1);
    float v = img[yc * W_DIM + xc];
    return valid ? v : 0.0f;
}

__global__ __launch_bounds__(256) void bilerp_kernel(
        const float* __restrict__ imgs,
        const float* __restrict__ dvfs,
        float* __restrict__ out) {
    __shared__ float tile[S_H * S_W];          // 25.6 KB -> 6 blocks/CU

    const int gx0 = blockIdx.x * TILE;
    const int gy0 = blockIdx.y * TILE;
    const int b   = blockIdx.z;
    const int tid = threadIdx.x;
    const int tx  = tid & 63;
    const int ty  = tid >> 6;

    const float*  __restrict__ img    = imgs + ((long long)b << HW_SHIFT);
    const double* __restrict__ dv_img =
        reinterpret_cast<const double*>(dvfs) + ((long long)b << HW_SHIFT);
    float* __restrict__ out_img = out + ((long long)b << HW_SHIFT);

    const int x = gx0 + tx;

    // ---- 1) issue all 16 dvf loads (independent; drain under staging) ----
    float2 d[16];
    #pragma unroll
    for (int i = 0; i < 16; ++i) {
        int y = gy0 + (i << 2) + ty;
        union { double u; float2 f; } cvt;
        cvt.u = __builtin_nontemporal_load(dv_img + ((y << 10) + x));
        d[i] = cvt.f;
    }

    // ---- 2) stage 80x80 neighborhood as float4 (zeros outside image) ----
    const int x_base = gx0 - HALO;
    const int y_base = gy0 - HALO;
    for (int q = tid; q < S_H * S_W4; q += 256) {
        int r = q / S_W4;                  // magic-mul div by 20
        int c = q - r * S_W4;
        int gy = y_base + r;
        int gx = x_base + (c << 2);
        float4 v = make_float4(0.f, 0.f, 0.f, 0.f);
        if ((unsigned)gy < (unsigned)H_DIM && (unsigned)gx < (unsigned)W_DIM)
            v = *reinterpret_cast<const float4*>(img + (gy << 10) + gx);
        *reinterpret_cast<float4*>(&tile[r * S_W + (c << 2)]) = v;
    }
    __syncthreads();

    // ---- 3) 16 independent output rows per thread (y = gy0 + 4i + ty) ----
    #pragma unroll
    for (int i = 0; i < 16; ++i) {
        int y = gy0 + (i << 2) + ty;
        float fx = (float)x + d[i].x;
        float fy = (float)y + d[i].y;
        float x0f = floorf(fx);
        float y0f = floorf(fy);
        float wx = fx - x0f;
        float wy = fy - y0f;
        int x0 = (int)x0f;
        int y0 = (int)y0f;
        int lx = x0 - x_base;
        int ly = y0 - y_base;

        float v00, v01, v10, v11;
        if ((unsigned)lx < (unsigned)(S_W - 1) &&
            (unsigned)ly < (unsigned)(S_H - 1)) {
            const float* p = &tile[ly * S_W + lx];
            v00 = p[0];
            v01 = p[1];
            v10 = p[S_W];
            v11 = p[S_W + 1];
        } else {                            // out-of-halo: ~never taken
            v00 = gather_zp(img, y0,     x0);
            v01 = gather_zp(img, y0,     x0 + 1);
            v10 = gather_zp(img, y0 + 1, x0);
            v11 = gather_zp(img, y0 + 1, x0 + 1);
        }

        float top = fmaf(wx, v01 - v00, v00);
        float bot = fmaf(wx, v11 - v10, v10);
        float res = fmaf(wy, bot - top, top);

        __builtin_nontemporal_store(res, out_img + ((y << 10) + x));
    }
}

extern "C" void kernel_launch(void* const* d_in, const int* in_sizes, int n_in,
                              void* d_out, int out_size, void* d_ws, size_t ws_size,
                              hipStream_t stream) {
    const float* imgs = (const float*)d_in[0];
    const float* dvfs = (const float*)d_in[1];
    float* out = (float*)d_out;

    dim3 grid(W_DIM / TILE, H_DIM / TILE, 32);   // 16 x 16 x 32 = 8192 blocks
    bilerp_kernel<<<grid, 256, 0, stream>>>(imgs, dvfs, out);
}